// Round 1
// baseline (455.313 us; speedup 1.0000x reference)
//
#include <hip/hip_runtime.h>

#define NB 128
#define T_DIM 50
#define Q_DIM 1024
#define H_DIM 256
#define S_DIM 49                 // MAX_STEP - 1
#define K_DIM (T_DIM * Q_DIM)    // 51200
#define KCHUNKS 25
#define KC (K_DIM / KCHUNKS)     // 2048
#define GRAM_N (NB * NB)         // 16384

typedef __attribute__((ext_vector_type(4))) float f32x4;
typedef __attribute__((ext_vector_type(8))) _Float16 half8v;
using pk2_t = decltype(__builtin_amdgcn_cvt_pkrtz(0.0f, 0.0f));

union Frag { half8v h8; pk2_t p2[4]; };

// Load 8 consecutive f32, convert to 8 f16 (RTZ, rel err 2^-11 -- far inside
// the 2% loss budget; fold-free since we keep raw-logit grams).
__device__ inline half8v load_frag_f16(const float* __restrict__ base) {
  const f32x4* p4 = (const f32x4*)base;
  f32x4 lo = p4[0];
  f32x4 hi = p4[1];
  Frag fr;
  fr.p2[0] = __builtin_amdgcn_cvt_pkrtz(lo[0], lo[1]);
  fr.p2[1] = __builtin_amdgcn_cvt_pkrtz(lo[2], lo[3]);
  fr.p2[2] = __builtin_amdgcn_cvt_pkrtz(hi[0], hi[1]);
  fr.p2[3] = __builtin_amdgcn_cvt_pkrtz(hi[2], hi[3]);
  return fr.h8;
}

// ---------------------------------------------------------------------------
// Kernel 1: partial gram matrices via 16x16x32 f16 MFMA.
// grid = (KCHUNKS, 9). gram id g: pair = g/3, kind = g%3 (0:xy, 1:xx, 2:yy).
// Block 256 = 4 waves; wave w owns the 64x64 output quadrant (w>>1, w&1).
// A-frag: A[m=lane&15][k=quad*8+j]; B-frag same on Y rows (G = X * Y^T).
// C/D: col = lane&15, row = quad*4 + reg   [m89-verified layout].
// ---------------------------------------------------------------------------
__global__ __launch_bounds__(256) void gram_partial_kernel(
    const float* __restrict__ s0, const float* __restrict__ s1, const float* __restrict__ s2,
    const float* __restrict__ t0, const float* __restrict__ t1, const float* __restrict__ t2,
    float* __restrict__ part) {
  const int g = blockIdx.y;
  const int pair = g / 3, kind = g % 3;
  const float* sp = (pair == 0) ? s0 : ((pair == 1) ? s1 : s2);
  const float* tp = (pair == 0) ? t0 : ((pair == 1) ? t1 : t2);
  const float* X = (kind == 2) ? tp : sp;
  const float* Y = (kind == 1) ? sp : tp;

  const int wave = threadIdx.x >> 6;
  const int lane = threadIdx.x & 63;
  const int r0 = (wave >> 1) * 64;
  const int c0 = (wave & 1) * 64;
  const int l15 = lane & 15;
  const int quad = lane >> 4;

  f32x4 acc[4][4];
#pragma unroll
  for (int i = 0; i < 4; i++)
#pragma unroll
    for (int j = 0; j < 4; j++)
      acc[i][j] = (f32x4){0.f, 0.f, 0.f, 0.f};

  const int kbase = blockIdx.x * KC;
  for (int k0 = kbase; k0 < kbase + KC; k0 += 32) {
    const int koff = k0 + quad * 8;
    half8v afr[4], bfr[4];
#pragma unroll
    for (int t = 0; t < 4; t++) {
      afr[t] = load_frag_f16(X + (size_t)(r0 + t * 16 + l15) * K_DIM + koff);
      bfr[t] = load_frag_f16(Y + (size_t)(c0 + t * 16 + l15) * K_DIM + koff);
    }
#pragma unroll
    for (int ti = 0; ti < 4; ti++)
#pragma unroll
      for (int tj = 0; tj < 4; tj++)
        acc[ti][tj] = __builtin_amdgcn_mfma_f32_16x16x32_f16(afr[ti], bfr[tj], acc[ti][tj], 0, 0, 0);
  }

  float* out = part + ((size_t)g * KCHUNKS + blockIdx.x) * GRAM_N;
#pragma unroll
  for (int ti = 0; ti < 4; ti++)
#pragma unroll
    for (int tj = 0; tj < 4; tj++)
#pragma unroll
      for (int r = 0; r < 4; r++)
        out[(size_t)(r0 + ti * 16 + quad * 4 + r) * NB + (c0 + tj * 16 + l15)] = acc[ti][tj][r];
}

// ---------------------------------------------------------------------------
// Kernel 2: reduce K-chunk partials -> gram[9][128][128]
// ---------------------------------------------------------------------------
__global__ __launch_bounds__(256) void gram_reduce_kernel(
    const float* __restrict__ part, float* __restrict__ gram) {
  const int idx = blockIdx.x * 256 + threadIdx.x;   // < 9*16384 = 147456
  const int g = idx >> 14;
  const int cell = idx & (GRAM_N - 1);
  const float* p = part + (size_t)g * KCHUNKS * GRAM_N + cell;
  float s = 0.f;
#pragma unroll
  for (int c = 0; c < KCHUNKS; c++) s += p[(size_t)c * GRAM_N];
  gram[idx] = s;
}

// ---------------------------------------------------------------------------
// Kernel 3: full Sinkhorn divergence per pair. 1 block of 512 per divergence.
// Groups of 128 threads compute ft / gt / faa / gbb in parallel (all read the
// OLD potentials, matching the reference's parallel update).
// C = 2*max(nx + ny - 2*gram, 0)  (the 1/TEMP^2 * 0.5 folding).
// Softmin evaluated in u = eps*h - C space (f32-stable; |u| ~ 2e5).
// ---------------------------------------------------------------------------
__global__ __launch_bounds__(512) void sinkhorn_kernel(
    const float* __restrict__ gram, float* __restrict__ kd) {
  const int p = blockIdx.x;
  const float* Gxy = gram + (size_t)(3 * p + 0) * GRAM_N;
  const float* Gxx = gram + (size_t)(3 * p + 1) * GRAM_N;
  const float* Gyy = gram + (size_t)(3 * p + 2) * GRAM_N;

  __shared__ float nx[NB], ny[NB];
  __shared__ float fab[NB], gab[NB], faa[NB], gbb[NB];
  __shared__ float nf[4][NB];
  __shared__ float red[512];

  const int tid = threadIdx.x;
  if (tid < NB) {
    nx[tid] = Gxx[tid * (NB + 1)];
    ny[tid] = Gyy[tid * (NB + 1)];
    fab[tid] = 0.f; gab[tid] = 0.f; faa[tid] = 0.f; gbb[tid] = 0.f;
  }
  __syncthreads();

  const float rho = 250000.0f;          // REACH^P
  const float AL = -4.852030263919617f; // -log(128)
  const int grp = tid >> 7;
  const int i = tid & (NB - 1);

  float eps = 1.0f;
  for (int it = 0; it < 9; it++) {
    if (it == 8) eps = 2.5e-5f;         // BLUR^P
    const float inv_eps = 1.0f / eps;
    const float damp = 1.0f / (1.0f + eps / rho);
    const float ebl = eps * AL;

    float m = -3.0e38f, s = 0.0f;
    if (grp == 0) {                     // ft: rows of Cxy, h from g_ab
      const float nxi = nx[i];
      const float* Grow = Gxy + i * NB;
      for (int j = 0; j < NB; j++) {
        float c = 2.0f * fmaxf(nxi + ny[j] - 2.0f * Grow[j], 0.0f);
        float u = ebl + gab[j] - c;
        float nm = fmaxf(m, u);
        s = s * __expf((m - nm) * inv_eps) + __expf((u - nm) * inv_eps);
        m = nm;
      }
      nf[0][i] = damp * (-(m + eps * __logf(s)));
    } else if (grp == 1) {              // gt: cols of Cxy, h from f_ab
      const float nyi = ny[i];
      for (int j = 0; j < NB; j++) {
        float c = 2.0f * fmaxf(nx[j] + nyi - 2.0f * Gxy[j * NB + i], 0.0f);
        float u = ebl + fab[j] - c;
        float nm = fmaxf(m, u);
        s = s * __expf((m - nm) * inv_eps) + __expf((u - nm) * inv_eps);
        m = nm;
      }
      nf[1][i] = damp * (-(m + eps * __logf(s)));
    } else if (grp == 2) {              // faa: rows of Cxx, h from f_aa
      const float nxi = nx[i];
      const float* Grow = Gxx + i * NB;
      for (int j = 0; j < NB; j++) {
        float c = 2.0f * fmaxf(nxi + nx[j] - 2.0f * Grow[j], 0.0f);
        float u = ebl + faa[j] - c;
        float nm = fmaxf(m, u);
        s = s * __expf((m - nm) * inv_eps) + __expf((u - nm) * inv_eps);
        m = nm;
      }
      nf[2][i] = 0.5f * (faa[i] + damp * (-(m + eps * __logf(s))));
    } else {                            // gbb: rows of Cyy, h from g_bb
      const float nyi = ny[i];
      const float* Grow = Gyy + i * NB;
      for (int j = 0; j < NB; j++) {
        float c = 2.0f * fmaxf(nyi + ny[j] - 2.0f * Grow[j], 0.0f);
        float u = ebl + gbb[j] - c;
        float nm = fmaxf(m, u);
        s = s * __expf((m - nm) * inv_eps) + __expf((u - nm) * inv_eps);
        m = nm;
      }
      nf[3][i] = 0.5f * (gbb[i] + damp * (-(m + eps * __logf(s))));
    }
    __syncthreads();
    if (tid < NB) {
      fab[tid] = nf[0][tid]; gab[tid] = nf[1][tid];
      faa[tid] = nf[2][tid]; gbb[tid] = nf[3][tid];
    }
    __syncthreads();
    eps *= 0.25f;                       // SCALING^P
  }

  float v = 0.f;
  if (tid < NB)
    v = __expf(-faa[tid] / rho) - __expf(-fab[tid] / rho)
      + __expf(-gbb[tid] / rho) - __expf(-gab[tid] / rho);
  red[tid] = v;
  __syncthreads();
  for (int st = 256; st > 0; st >>= 1) {
    if (tid < st) red[tid] += red[tid + st];
    __syncthreads();
  }
  if (tid == 0) kd[p] = (250000.0000125f / 128.0f) * red[0];  // w * a_w
}

// ---------------------------------------------------------------------------
// Kernel 4: exploit the exact one-hot structure of delta.
// block per (b,s): scan batch row t=s+1 for the single q with oh==1,
// then gather the 3 logits at (b, s, q) and the correctness bit.
// ---------------------------------------------------------------------------
__global__ __launch_bounds__(256) void ps_kernel(
    const float* __restrict__ lc, const float* __restrict__ lt, const float* __restrict__ le,
    const float* __restrict__ batch,
    float* __restrict__ pc, float* __restrict__ pt, float* __restrict__ pe,
    float* __restrict__ aarr) {
  const int bs = blockIdx.x;
  const int b = bs / S_DIM, s = bs % S_DIM;
  const float* brow = batch + ((size_t)b * T_DIM + (s + 1)) * (2 * Q_DIM);
  __shared__ int sq;
  __shared__ float sds;
  if (threadIdx.x == 0) sq = 0;
  __syncthreads();
  for (int q = threadIdx.x; q < Q_DIM; q += 256) {
    float d0 = brow[q], d1 = brow[Q_DIM + q];
    if (d0 + d1 > 0.5f) { sq = q; sds = d0 - d1; }   // exactly one thread fires
  }
  __syncthreads();
  if (threadIdx.x == 0) {
    const size_t off = ((size_t)b * T_DIM + s) * Q_DIM + sq;
    pc[bs] = 2.0f * lc[off];   // 1/TEMP
    pt[bs] = 2.0f * lt[off];
    pe[bs] = 2.0f * le[off];
    aarr[bs] = (sds > 0.0f) ? 1.0f : 0.0f;   // a = correct[b, s+1]
  }
}

// ---------------------------------------------------------------------------
// Kernel 5: embed loss: sum of squared diffs, float4 grid-stride + atomicAdd.
// ---------------------------------------------------------------------------
__global__ __launch_bounds__(256) void embed_kernel(
    const f32x4* __restrict__ hs, const f32x4* __restrict__ ht,
    const f32x4* __restrict__ ds, const f32x4* __restrict__ dt,
    float* __restrict__ acc) {
  const int N4 = NB * T_DIM * H_DIM / 4;   // 409600
  float sum = 0.f;
  for (int idx = blockIdx.x * 256 + threadIdx.x; idx < N4; idx += gridDim.x * 256) {
    f32x4 a = hs[idx] - ht[idx];
    f32x4 b = ds[idx] - dt[idx];
    sum += a[0]*a[0] + a[1]*a[1] + a[2]*a[2] + a[3]*a[3]
         + b[0]*b[0] + b[1]*b[1] + b[2]*b[2] + b[3]*b[3];
  }
  for (int off = 32; off > 0; off >>= 1) sum += __shfl_down(sum, off, 64);
  __shared__ float wsum[4];
  const int lane = threadIdx.x & 63, wv = threadIdx.x >> 6;
  if (lane == 0) wsum[wv] = sum;
  __syncthreads();
  if (threadIdx.x == 0) atomicAdd(acc, wsum[0] + wsum[1] + wsum[2] + wsum[3]);
}

// ---------------------------------------------------------------------------
// Kernel 6: masked CE over S=49 steps per row + final combine. 1 block, 128 thr.
// ---------------------------------------------------------------------------
__device__ inline float ce_row(const float* __restrict__ x, const float* __restrict__ a, int L) {
  float m = -3.0e38f;
  for (int s = 0; s < L; s++) m = fmaxf(m, x[s]);
  float sum = 0.f;
  for (int s = 0; s < L; s++) sum += __expf(x[s] - m);
  const float lse = m + __logf(sum);
  float loss = 0.f;
  for (int s = 0; s < L; s++) loss += a[s] * (x[s] - lse);
  return -loss;
}

__global__ __launch_bounds__(128) void ce_final_kernel(
    const float* __restrict__ pc, const float* __restrict__ pt, const float* __restrict__ pe,
    const float* __restrict__ aarr, const float* __restrict__ kd,
    const float* __restrict__ emb, float* __restrict__ out) {
  const int b = threadIdx.x;
  const float* xc = pc + b * S_DIM;
  const float* xt = pt + b * S_DIM;
  const float* xe = pe + b * S_DIM;
  const float* av = aarr + b * S_DIM;
  int last = -1;
  for (int s = 0; s < S_DIM; s++)
    if (xc[s] > 0.0f) last = s;
  const int L = (last >= 0) ? (last + 1) : S_DIM;
  float loss = ce_row(xt, av, L) + ce_row(xc, av, L) + ce_row(xe, av, L);
  __shared__ float red[128];
  red[b] = loss;
  __syncthreads();
  for (int st = 64; st > 0; st >>= 1) {
    if (b < st) red[b] += red[b + st];
    __syncthreads();
  }
  if (b == 0)
    out[0] = red[0] + 0.01f * (kd[0] + kd[1] + kd[2]) + 0.5f * emb[0];
}

// ---------------------------------------------------------------------------
extern "C" void kernel_launch(void* const* d_in, const int* in_sizes, int n_in,
                              void* d_out, int out_size, void* d_ws, size_t ws_size,
                              hipStream_t stream) {
  const float* lc    = (const float*)d_in[0];
  const float* lt    = (const float*)d_in[1];
  const float* le    = (const float*)d_in[2];
  const float* ltc   = (const float*)d_in[3];
  const float* ltt   = (const float*)d_in[4];
  const float* lte   = (const float*)d_in[5];
  const float* ohs   = (const float*)d_in[6];
  const float* oht   = (const float*)d_in[7];
  const float* ods   = (const float*)d_in[8];
  const float* odt   = (const float*)d_in[9];
  const float* batch = (const float*)d_in[10];

  float* ws   = (float*)d_ws;
  float* gram = ws;                                   // 9 * 16384
  float* part = gram + 9 * GRAM_N;                    // 9 * 25 * 16384
  float* pcb  = part + (size_t)9 * KCHUNKS * GRAM_N;  // 128*49
  float* ptb  = pcb + NB * S_DIM;
  float* peb  = ptb + NB * S_DIM;
  float* ab   = peb + NB * S_DIM;
  float* kd   = ab + NB * S_DIM;                      // 3
  float* emb  = kd + 3;                               // 1

  hipMemsetAsync(emb, 0, sizeof(float), stream);

  embed_kernel<<<512, 256, 0, stream>>>(
      (const f32x4*)ohs, (const f32x4*)oht, (const f32x4*)ods, (const f32x4*)odt, emb);

  ps_kernel<<<NB * S_DIM, 256, 0, stream>>>(lc, lt, le, batch, pcb, ptb, peb, ab);

  gram_partial_kernel<<<dim3(KCHUNKS, 9), 256, 0, stream>>>(lc, lt, le, ltc, ltt, lte, part);

  gram_reduce_kernel<<<(9 * GRAM_N) / 256, 256, 0, stream>>>(part, gram);

  sinkhorn_kernel<<<3, 512, 0, stream>>>(gram, kd);

  ce_final_kernel<<<1, 128, 0, stream>>>(pcb, ptb, peb, ab, kd, emb, (float*)d_out);
}

// Round 2
// 389.074 us; speedup vs baseline: 1.1702x; 1.1702x over previous
//
#include <hip/hip_runtime.h>

#define NB 128
#define T_DIM 50
#define Q_DIM 1024
#define H_DIM 256
#define S_DIM 49                 // MAX_STEP - 1
#define K_DIM 51200              // T*Q
#define KCHUNKS 40
#define KC 1280                  // K per block (= K_DIM/KCHUNKS)
#define BK 64                    // K per LDS stage
#define GRAM_N (NB * NB)         // 16384
#define LROWU 36                 // uints per padded LDS row (64 f16 + 8 pad)

typedef __attribute__((ext_vector_type(4))) float f32x4;
typedef __attribute__((ext_vector_type(8))) _Float16 half8v;
typedef __attribute__((ext_vector_type(4))) unsigned int uint4v;
typedef __attribute__((ext_vector_type(2))) unsigned int uint2v;
using pk2_t = decltype(__builtin_amdgcn_cvt_pkrtz(0.0f, 0.0f));

union PKU { pk2_t p; unsigned int u; };
union U4H8 { uint4v u; half8v h; };

__device__ inline unsigned short f2bf(float x) {
  union { float f; unsigned int u; } v; v.f = x;
  return (unsigned short)(v.u >> 16);   // truncate; <=1 ULP(512 @2e5) -- inside budget
}
__device__ inline float bf2f(unsigned short b) {
  union { float f; unsigned int u; } v; v.u = ((unsigned int)b) << 16;
  return v.f;
}

// ---------------------------------------------------------------------------
// Kernel 1: partial grams via 16x16x32 f16 MFMA with LDS-staged f16 panels.
// grid = (KCHUNKS, 9), block = 512 (8 waves). Wave w: rhalf = w>>2 (64 rows),
// colq = w&3 (32 cols); acc[4][2] 16x16 tiles.
// LDS rows padded to 72 f16 (36 uints) -> fragment ds_read_b128 is 2-way max.
// ---------------------------------------------------------------------------
__global__ __launch_bounds__(512) void gram_tile_kernel(
    const float* __restrict__ s0, const float* __restrict__ s1, const float* __restrict__ s2,
    const float* __restrict__ t0, const float* __restrict__ t1, const float* __restrict__ t2,
    float* __restrict__ part) {
  __shared__ unsigned int panA[NB * LROWU];   // 18432 B
  __shared__ unsigned int panB[NB * LROWU];   // 18432 B

  const int g = blockIdx.y;
  const int pair = g / 3, kind = g % 3;
  const float* sp = (pair == 0) ? s0 : ((pair == 1) ? s1 : s2);
  const float* tp = (pair == 0) ? t0 : ((pair == 1) ? t1 : t2);
  const float* X = (kind == 2) ? tp : sp;     // xx: s, yy: t, xy: s
  const float* Y = (kind == 1) ? sp : tp;     // xx: s, yy: t, xy: t

  const int tid = threadIdx.x;
  const int wave = tid >> 6, lane = tid & 63;
  const int rhalf = wave >> 2, colq = wave & 3;
  const int l15 = lane & 15, quad = lane >> 4;

  f32x4 acc[4][2];
#pragma unroll
  for (int i = 0; i < 4; i++)
#pragma unroll
    for (int j = 0; j < 2; j++)
      acc[i][j] = (f32x4){0.f, 0.f, 0.f, 0.f};

  const int kbase = blockIdx.x * KC;
  for (int ks0 = 0; ks0 < KC; ks0 += BK) {
    __syncthreads();   // previous-stage reads done before overwrite
    // ---- stage 128 x 64 f32 -> f16 LDS, both matrices ----
#pragma unroll
    for (int m = 0; m < 2; m++) {
      const float* src = m ? Y : X;
      unsigned int* pan = m ? panB : panA;
#pragma unroll
      for (int i = 0; i < 4; i++) {
        const int f4 = tid + 512 * i;          // 0..2047
        const int row = f4 >> 4, kq = f4 & 15; // 16 float4 per row
        const f32x4 v = *(const f32x4*)(src + (size_t)row * K_DIM + (kbase + ks0 + kq * 4));
        PKU a, b;
        a.p = __builtin_amdgcn_cvt_pkrtz(v[0], v[1]);
        b.p = __builtin_amdgcn_cvt_pkrtz(v[2], v[3]);
        uint2v w; w.x = a.u; w.y = b.u;
        *(uint2v*)&pan[row * LROWU + kq * 2] = w;
      }
    }
    __syncthreads();
    // ---- 2 k-steps of 32 ----
#pragma unroll
    for (int ks = 0; ks < 2; ks++) {
      half8v af[4], bf[2];
#pragma unroll
      for (int t = 0; t < 4; t++) {
        const int row = rhalf * 64 + t * 16 + l15;
        U4H8 u; u.u = *(const uint4v*)&panA[row * LROWU + ks * 16 + quad * 4];
        af[t] = u.h;
      }
#pragma unroll
      for (int t = 0; t < 2; t++) {
        const int row = colq * 32 + t * 16 + l15;
        U4H8 u; u.u = *(const uint4v*)&panB[row * LROWU + ks * 16 + quad * 4];
        bf[t] = u.h;
      }
#pragma unroll
      for (int ti = 0; ti < 4; ti++)
#pragma unroll
        for (int tj = 0; tj < 2; tj++)
          acc[ti][tj] = __builtin_amdgcn_mfma_f32_16x16x32_f16(af[ti], bf[tj], acc[ti][tj], 0, 0, 0);
    }
  }

  float* out = part + ((size_t)g * KCHUNKS + blockIdx.x) * GRAM_N;
#pragma unroll
  for (int ti = 0; ti < 4; ti++)
#pragma unroll
    for (int tj = 0; tj < 2; tj++)
#pragma unroll
      for (int r = 0; r < 4; r++) {
        const int row = rhalf * 64 + ti * 16 + quad * 4 + r;
        const int col = colq * 32 + tj * 16 + l15;
        out[(size_t)row * NB + col] = acc[ti][tj][r];
      }
}

// ---------------------------------------------------------------------------
// Kernel 2: reduce K-chunk partials -> gram[9][128][128]
// ---------------------------------------------------------------------------
__global__ __launch_bounds__(256) void gram_reduce_kernel(
    const float* __restrict__ part, float* __restrict__ gram) {
  const int idx = blockIdx.x * 256 + threadIdx.x;   // < 9*16384
  const int g = idx >> 14;
  const int cell = idx & (GRAM_N - 1);
  const float* p = part + (size_t)g * KCHUNKS * GRAM_N + cell;
  float s = 0.f;
#pragma unroll
  for (int c = 0; c < KCHUNKS; c++) s += p[(size_t)c * GRAM_N];
  gram[idx] = s;
}

// ---------------------------------------------------------------------------
// Kernel 3: Sinkhorn, split 3 ways per pair (xy / xx / yy chains are
// independent). grid = (3 pairs, 3 kinds), block 256.
//   kind 0: grp0 = ft (reads g_ab, C rows), grp1 = gt (reads f_ab, C cols)
//   kind 1: faa (self, C=Cxx rows);  kind 2: gbb (self, C=Cyy rows)
// Cost matrix staged in LDS as bf16, rows padded to 132 (row & col reads
// both <=2-way bank aliasing = free). Softmin in u = eps*h - C space with
// 4-way ILP split of the running logsumexp.
// Outputs kdpart[pair*3+kind] = (+/-) sum of exp terms; combined in kernel 6.
// ---------------------------------------------------------------------------
__global__ __launch_bounds__(256) void sinkhorn_part_kernel(
    const float* __restrict__ gram, float* __restrict__ kdpart) {
  const int pair = blockIdx.x, kind = blockIdx.y;
  const float* Gxy = gram + (size_t)(3 * pair + 0) * GRAM_N;
  const float* Gxx = gram + (size_t)(3 * pair + 1) * GRAM_N;
  const float* Gyy = gram + (size_t)(3 * pair + 2) * GRAM_N;

  __shared__ unsigned short C[NB][132];     // 33792 B
  __shared__ float nx[NB], ny[NB];
  __shared__ float pot0[NB], pot1[NB];
  __shared__ float np0[NB], np1[NB];
  __shared__ float red[256];

  const int tid = threadIdx.x;
  if (tid < NB) {
    nx[tid] = Gxx[tid * (NB + 1)];
    ny[tid] = Gyy[tid * (NB + 1)];
    pot0[tid] = 0.f; pot1[tid] = 0.f;
  }
  __syncthreads();

  const float* G  = (kind == 0) ? Gxy : ((kind == 1) ? Gxx : Gyy);
  const float* rn = (kind == 2) ? ny : nx;
  const float* cn = (kind == 1) ? nx : ny;
  for (int idx = tid; idx < GRAM_N; idx += 256) {
    const int i = idx >> 7, j = idx & 127;
    const float c = 2.0f * fmaxf(rn[i] + cn[j] - 2.0f * G[idx], 0.0f);
    C[i][j] = f2bf(c);
  }
  __syncthreads();

  const float rho = 250000.0f;
  const float AL = -4.852030263919617f;     // -log(128)
  const int grp = tid >> 7;
  const int i = tid & 127;
  const bool active = (kind == 0) ? true : (grp == 0);
  const bool colread = (kind == 0) && (grp == 1);

  float eps = 1.0f;
  for (int it = 0; it < 9; it++) {
    if (it == 8) eps = 2.5e-5f;             // BLUR^P
    const float inv_eps = 1.0f / eps;
    const float damp = 1.0f / (1.0f + eps / rho);
    const float ebl = eps * AL;

    if (active) {
      // h vector: ft uses g_ab(pot1); gt uses f_ab(pot0); self-kinds use pot0
      const float* h = (kind == 0 && grp == 0) ? pot1 : pot0;
      float m0 = -3.0e38f, m1 = -3.0e38f, m2 = -3.0e38f, m3 = -3.0e38f;
      float s0 = 0.f, s1 = 0.f, s2 = 0.f, s3 = 0.f;
      for (int j = 0; j < NB; j += 4) {
        float c0, c1, c2, c3;
        if (colread) {
          c0 = bf2f(C[j + 0][i]); c1 = bf2f(C[j + 1][i]);
          c2 = bf2f(C[j + 2][i]); c3 = bf2f(C[j + 3][i]);
        } else {
          c0 = bf2f(C[i][j + 0]); c1 = bf2f(C[i][j + 1]);
          c2 = bf2f(C[i][j + 2]); c3 = bf2f(C[i][j + 3]);
        }
        const float u0 = ebl + h[j + 0] - c0;
        const float u1 = ebl + h[j + 1] - c1;
        const float u2 = ebl + h[j + 2] - c2;
        const float u3 = ebl + h[j + 3] - c3;
        float nm;
        nm = fmaxf(m0, u0); s0 = s0 * __expf((m0 - nm) * inv_eps) + __expf((u0 - nm) * inv_eps); m0 = nm;
        nm = fmaxf(m1, u1); s1 = s1 * __expf((m1 - nm) * inv_eps) + __expf((u1 - nm) * inv_eps); m1 = nm;
        nm = fmaxf(m2, u2); s2 = s2 * __expf((m2 - nm) * inv_eps) + __expf((u2 - nm) * inv_eps); m2 = nm;
        nm = fmaxf(m3, u3); s3 = s3 * __expf((m3 - nm) * inv_eps) + __expf((u3 - nm) * inv_eps); m3 = nm;
      }
      const float M = fmaxf(fmaxf(m0, m1), fmaxf(m2, m3));
      const float S = s0 * __expf((m0 - M) * inv_eps) + s1 * __expf((m1 - M) * inv_eps)
                    + s2 * __expf((m2 - M) * inv_eps) + s3 * __expf((m3 - M) * inv_eps);
      const float sm = -(M + eps * __logf(S));
      float newp;
      if (kind == 0) newp = damp * sm;
      else           newp = 0.5f * (pot0[i] + damp * sm);
      if (grp == 0) np0[i] = newp; else np1[i] = newp;
    }
    __syncthreads();
    if (tid < NB) {
      pot0[tid] = np0[tid];
      if (kind == 0) pot1[tid] = np1[tid];
    }
    __syncthreads();
    eps *= 0.25f;                           // SCALING^P
  }

  float v = 0.f;
  if (kind == 0) {
    v = (grp == 0) ? -__expf(-pot0[i] / rho)   // -exp(-f_ab/rho)
                   : -__expf(-pot1[i] / rho);  // -exp(-g_ab/rho)
  } else if (grp == 0) {
    v = __expf(-pot0[i] / rho);               // +exp(-f_aa or -g_bb /rho)
  }
  red[tid] = v;
  __syncthreads();
  for (int st = 128; st > 0; st >>= 1) {
    if (tid < st) red[tid] += red[tid + st];
    __syncthreads();
  }
  if (tid == 0) kdpart[pair * 3 + kind] = red[0];
}

// ---------------------------------------------------------------------------
// Kernel 4: one-hot structure of delta -> gathers. block per (b,s).
// ---------------------------------------------------------------------------
__global__ __launch_bounds__(256) void ps_kernel(
    const float* __restrict__ lc, const float* __restrict__ lt, const float* __restrict__ le,
    const float* __restrict__ batch,
    float* __restrict__ pc, float* __restrict__ pt, float* __restrict__ pe,
    float* __restrict__ aarr) {
  const int bs = blockIdx.x;
  const int b = bs / S_DIM, s = bs % S_DIM;
  const float* brow = batch + ((size_t)b * T_DIM + (s + 1)) * (2 * Q_DIM);
  __shared__ int sq;
  __shared__ float sds;
  if (threadIdx.x == 0) sq = 0;
  __syncthreads();
  for (int q = threadIdx.x; q < Q_DIM; q += 256) {
    float d0 = brow[q], d1 = brow[Q_DIM + q];
    if (d0 + d1 > 0.5f) { sq = q; sds = d0 - d1; }   // exactly one thread fires
  }
  __syncthreads();
  if (threadIdx.x == 0) {
    const size_t off = ((size_t)b * T_DIM + s) * Q_DIM + sq;
    pc[bs] = 2.0f * lc[off];   // 1/TEMP
    pt[bs] = 2.0f * lt[off];
    pe[bs] = 2.0f * le[off];
    aarr[bs] = (sds > 0.0f) ? 1.0f : 0.0f;
  }
}

// ---------------------------------------------------------------------------
// Kernel 5: embed loss: sum of squared diffs.
// ---------------------------------------------------------------------------
__global__ __launch_bounds__(256) void embed_kernel(
    const f32x4* __restrict__ hs, const f32x4* __restrict__ ht,
    const f32x4* __restrict__ ds, const f32x4* __restrict__ dt,
    float* __restrict__ acc) {
  const int N4 = NB * T_DIM * H_DIM / 4;   // 409600
  float sum = 0.f;
  for (int idx = blockIdx.x * 256 + threadIdx.x; idx < N4; idx += gridDim.x * 256) {
    f32x4 a = hs[idx] - ht[idx];
    f32x4 b = ds[idx] - dt[idx];
    sum += a[0]*a[0] + a[1]*a[1] + a[2]*a[2] + a[3]*a[3]
         + b[0]*b[0] + b[1]*b[1] + b[2]*b[2] + b[3]*b[3];
  }
  for (int off = 32; off > 0; off >>= 1) sum += __shfl_down(sum, off, 64);
  __shared__ float wsum[4];
  const int lane = threadIdx.x & 63, wv = threadIdx.x >> 6;
  if (lane == 0) wsum[wv] = sum;
  __syncthreads();
  if (threadIdx.x == 0) atomicAdd(acc, wsum[0] + wsum[1] + wsum[2] + wsum[3]);
}

// ---------------------------------------------------------------------------
// Kernel 6: masked CE + final combine. 1 block, 128 threads.
// ---------------------------------------------------------------------------
__device__ inline float ce_row(const float* __restrict__ x, const float* __restrict__ a, int L) {
  float m = -3.0e38f;
  for (int s = 0; s < L; s++) m = fmaxf(m, x[s]);
  float sum = 0.f;
  for (int s = 0; s < L; s++) sum += __expf(x[s] - m);
  const float lse = m + __logf(sum);
  float loss = 0.f;
  for (int s = 0; s < L; s++) loss += a[s] * (x[s] - lse);
  return -loss;
}

__global__ __launch_bounds__(128) void ce_final_kernel(
    const float* __restrict__ pc, const float* __restrict__ pt, const float* __restrict__ pe,
    const float* __restrict__ aarr, const float* __restrict__ kdpart,
    const float* __restrict__ emb, float* __restrict__ out) {
  const int b = threadIdx.x;
  const float* xc = pc + b * S_DIM;
  const float* xt = pt + b * S_DIM;
  const float* xe = pe + b * S_DIM;
  const float* av = aarr + b * S_DIM;
  int last = -1;
  for (int s = 0; s < S_DIM; s++)
    if (xc[s] > 0.0f) last = s;
  const int L = (last >= 0) ? (last + 1) : S_DIM;
  float loss = ce_row(xt, av, L) + ce_row(xc, av, L) + ce_row(xe, av, L);
  __shared__ float red[128];
  red[b] = loss;
  __syncthreads();
  for (int st = 64; st > 0; st >>= 1) {
    if (b < st) red[b] += red[b + st];
    __syncthreads();
  }
  if (b == 0) {
    float kd = 0.f;
    for (int k = 0; k < 9; k++) kd += kdpart[k];
    // w * a_w = (rho + eps_final/2) / 128 ; DIST_W = 0.01
    out[0] = red[0] + 0.01f * (250000.0000125f / 128.0f) * kd + 0.5f * emb[0];
  }
}

// ---------------------------------------------------------------------------
extern "C" void kernel_launch(void* const* d_in, const int* in_sizes, int n_in,
                              void* d_out, int out_size, void* d_ws, size_t ws_size,
                              hipStream_t stream) {
  const float* lc    = (const float*)d_in[0];
  const float* lt    = (const float*)d_in[1];
  const float* le    = (const float*)d_in[2];
  const float* ltc   = (const float*)d_in[3];
  const float* ltt   = (const float*)d_in[4];
  const float* lte   = (const float*)d_in[5];
  const float* ohs   = (const float*)d_in[6];
  const float* oht   = (const float*)d_in[7];
  const float* ods   = (const float*)d_in[8];
  const float* odt   = (const float*)d_in[9];
  const float* batch = (const float*)d_in[10];

  float* ws   = (float*)d_ws;
  float* part = ws;                                   // 9*40*16384 = 23.6 MB
  float* gram = part + (size_t)9 * KCHUNKS * GRAM_N;  // 9*16384
  float* pcb  = gram + 9 * GRAM_N;                    // 128*49 each
  float* ptb  = pcb + NB * S_DIM;
  float* peb  = ptb + NB * S_DIM;
  float* ab   = peb + NB * S_DIM;
  float* kdp  = ab + NB * S_DIM;                      // 9
  float* emb  = kdp + 9;                              // 1

  hipMemsetAsync(emb, 0, sizeof(float), stream);

  embed_kernel<<<512, 256, 0, stream>>>(
      (const f32x4*)ohs, (const f32x4*)oht, (const f32x4*)ods, (const f32x4*)odt, emb);

  ps_kernel<<<NB * S_DIM, 256, 0, stream>>>(lc, lt, le, batch, pcb, ptb, peb, ab);

  gram_tile_kernel<<<dim3(KCHUNKS, 9), 512, 0, stream>>>(lc, lt, le, ltc, ltt, lte, part);

  gram_reduce_kernel<<<(9 * GRAM_N) / 256, 256, 0, stream>>>(part, gram);

  sinkhorn_part_kernel<<<dim3(3, 3), 256, 0, stream>>>(gram, kdp);

  ce_final_kernel<<<1, 128, 0, stream>>>(pcb, ptb, peb, ab, kdp, emb, (float*)d_out);
}

// Round 3
// 376.954 us; speedup vs baseline: 1.2079x; 1.0322x over previous
//
#include <hip/hip_runtime.h>

#define NB 128
#define T_DIM 50
#define Q_DIM 1024
#define H_DIM 256
#define S_DIM 49                 // MAX_STEP - 1
#define K_DIM 51200              // T*Q
#define KCHUNKS 80
#define KC 640                   // K per block
#define BK 64                    // K per LDS stage
#define NSTAGE 10                // KC/BK
#define GRAM_N (NB * NB)         // 16384
#define LROWU 36                 // uints per padded LDS row (64 f16 + 8 pad)

typedef __attribute__((ext_vector_type(4))) float f32x4;
typedef __attribute__((ext_vector_type(8))) _Float16 half8v;
typedef __attribute__((ext_vector_type(4))) unsigned int uint4v;
typedef __attribute__((ext_vector_type(2))) unsigned int uint2v;
using pk2_t = decltype(__builtin_amdgcn_cvt_pkrtz(0.0f, 0.0f));

union PKU { pk2_t p; unsigned int u; };
union U4H8 { uint4v u; half8v h; };

__device__ inline unsigned short f2bf_rn(float x) {   // round-nearest-even bf16
  union { float f; unsigned int u; } v; v.f = x;
  unsigned int r = v.u + 0x7FFFu + ((v.u >> 16) & 1u);
  return (unsigned short)(r >> 16);
}
__device__ inline float bf2f(unsigned short b) {
  union { float f; unsigned int u; } v; v.u = ((unsigned int)b) << 16;
  return v.f;
}

// ---------------------------------------------------------------------------
// Kernel 1: FUSED per-pair grams (XY, XX, YY) via 16x16x32 f16 MFMA.
// grid = (KCHUNKS, 3 pairs), block = 1024 (16 waves).
// Staging: s-panel and t-panel (128 x 64 f32 -> f16) read ONCE, all three
// grams computed from LDS -> logical global reads = 157 MB total (compulsory).
// Register-prefetch pipeline: next stage's 4 float4 loads issue before the
// current stage's compute, hiding load latency under 24 MFMA + 16 ds_read.
// Wave w: rows (w>>2)*32, cols (w&3)*32. acc 2x2 tiles per gram (48 VGPR acc,
// ~115 total -> 4 waves/SIMD).
// C/D layout: col=lane&15, row=quad*4+reg   [m89-verified].
// Partials stored as bf16(rn): ws stays 23.6 MB; error ~1e1 on C~2e5 scale,
// ~0.4 absolute on the final output (threshold 6.7e4).
// ---------------------------------------------------------------------------
__global__ __launch_bounds__(1024) void gram_fused_kernel(
    const float* __restrict__ s0, const float* __restrict__ s1, const float* __restrict__ s2,
    const float* __restrict__ t0, const float* __restrict__ t1, const float* __restrict__ t2,
    unsigned short* __restrict__ part) {
  __shared__ unsigned int panA[NB * LROWU];   // s panel, 18432 B
  __shared__ unsigned int panB[NB * LROWU];   // t panel, 18432 B

  const int chunk = blockIdx.x;
  const int pair = blockIdx.y;
  const float* S  = (pair == 0) ? s0 : ((pair == 1) ? s1 : s2);
  const float* Tm = (pair == 0) ? t0 : ((pair == 1) ? t1 : t2);

  const int tid = threadIdx.x;
  const int wave = tid >> 6, lane = tid & 63;
  const int wrow = wave >> 2, wcol = wave & 3;
  const int l15 = lane & 15, quad = lane >> 4;

  f32x4 aXY[2][2], aXX[2][2], aYY[2][2];
#pragma unroll
  for (int i = 0; i < 2; i++)
#pragma unroll
    for (int j = 0; j < 2; j++) {
      aXY[i][j] = (f32x4){0.f, 0.f, 0.f, 0.f};
      aXX[i][j] = (f32x4){0.f, 0.f, 0.f, 0.f};
      aYY[i][j] = (f32x4){0.f, 0.f, 0.f, 0.f};
    }

  // staging geometry: 1024 threads cover 2048 float4 = 128 rows x 16 per panel
  const int r0 = tid >> 4;              // 0..63 (i=0); i=1 -> r0+64
  const int kq = tid & 15;
  const size_t ro0 = (size_t)r0 * K_DIM;
  const size_t ro1 = (size_t)(r0 + 64) * K_DIM;

  const int kbase = chunk * KC;
  f32x4 pre0, pre1, pre2, pre3;

#define ISSUE_LOADS(KPOS)                                    \
  {                                                          \
    const float* pS = S + (KPOS) + kq * 4;                   \
    const float* pT = Tm + (KPOS) + kq * 4;                  \
    pre0 = *(const f32x4*)(pS + ro0);                        \
    pre1 = *(const f32x4*)(pS + ro1);                        \
    pre2 = *(const f32x4*)(pT + ro0);                        \
    pre3 = *(const f32x4*)(pT + ro1);                        \
  }

  ISSUE_LOADS(kbase)

  for (int st = 0; st < NSTAGE; st++) {
    if (st) __syncthreads();            // readers of stage st-1 done
    {                                   // cvt + LDS write (waits vmcnt here)
      PKU a, b; uint2v w;
      a.p = __builtin_amdgcn_cvt_pkrtz(pre0[0], pre0[1]);
      b.p = __builtin_amdgcn_cvt_pkrtz(pre0[2], pre0[3]);
      w.x = a.u; w.y = b.u;
      *(uint2v*)&panA[r0 * LROWU + kq * 2] = w;
      a.p = __builtin_amdgcn_cvt_pkrtz(pre1[0], pre1[1]);
      b.p = __builtin_amdgcn_cvt_pkrtz(pre1[2], pre1[3]);
      w.x = a.u; w.y = b.u;
      *(uint2v*)&panA[(r0 + 64) * LROWU + kq * 2] = w;
      a.p = __builtin_amdgcn_cvt_pkrtz(pre2[0], pre2[1]);
      b.p = __builtin_amdgcn_cvt_pkrtz(pre2[2], pre2[3]);
      w.x = a.u; w.y = b.u;
      *(uint2v*)&panB[r0 * LROWU + kq * 2] = w;
      a.p = __builtin_amdgcn_cvt_pkrtz(pre3[0], pre3[1]);
      b.p = __builtin_amdgcn_cvt_pkrtz(pre3[2], pre3[3]);
      w.x = a.u; w.y = b.u;
      *(uint2v*)&panB[(r0 + 64) * LROWU + kq * 2] = w;
    }
    __syncthreads();                    // writes visible
    if (st + 1 < NSTAGE) ISSUE_LOADS(kbase + (st + 1) * BK)  // prefetch flies under compute

#pragma unroll
    for (int ks = 0; ks < 2; ks++) {
      const int kc = ks * 16 + quad * 4;
      half8v as_[2], bs_[2], at_[2], bt_[2];
#pragma unroll
      for (int t = 0; t < 2; t++) {
        U4H8 u;
        u.u = *(const uint4v*)&panA[(wrow * 32 + t * 16 + l15) * LROWU + kc]; as_[t] = u.h;
        u.u = *(const uint4v*)&panA[(wcol * 32 + t * 16 + l15) * LROWU + kc]; bs_[t] = u.h;
        u.u = *(const uint4v*)&panB[(wrow * 32 + t * 16 + l15) * LROWU + kc]; at_[t] = u.h;
        u.u = *(const uint4v*)&panB[(wcol * 32 + t * 16 + l15) * LROWU + kc]; bt_[t] = u.h;
      }
#pragma unroll
      for (int ti = 0; ti < 2; ti++)
#pragma unroll
        for (int tj = 0; tj < 2; tj++) {
          aXY[ti][tj] = __builtin_amdgcn_mfma_f32_16x16x32_f16(as_[ti], bt_[tj], aXY[ti][tj], 0, 0, 0);
          aXX[ti][tj] = __builtin_amdgcn_mfma_f32_16x16x32_f16(as_[ti], bs_[tj], aXX[ti][tj], 0, 0, 0);
          aYY[ti][tj] = __builtin_amdgcn_mfma_f32_16x16x32_f16(at_[ti], bt_[tj], aYY[ti][tj], 0, 0, 0);
        }
    }
  }
#undef ISSUE_LOADS

  // epilogue: bf16 partials, layout part[(g*KCHUNKS + chunk)][128][128]
#pragma unroll
  for (int kind = 0; kind < 3; kind++) {
    unsigned short* out = part + ((size_t)(pair * 3 + kind) * KCHUNKS + chunk) * GRAM_N;
#pragma unroll
    for (int ti = 0; ti < 2; ti++)
#pragma unroll
      for (int tj = 0; tj < 2; tj++) {
        const f32x4 v = (kind == 0) ? aXY[ti][tj] : ((kind == 1) ? aXX[ti][tj] : aYY[ti][tj]);
        const int col = wcol * 32 + tj * 16 + l15;
#pragma unroll
        for (int r = 0; r < 4; r++) {
          const int row = wrow * 32 + ti * 16 + quad * 4 + r;
          out[(size_t)row * NB + col] = f2bf_rn(v[r]);
        }
      }
  }
}

// ---------------------------------------------------------------------------
// Kernel 2: reduce bf16 K-chunk partials -> gram[9][128][128] (f32)
// ---------------------------------------------------------------------------
__global__ __launch_bounds__(256) void gram_reduce_kernel(
    const unsigned short* __restrict__ part, float* __restrict__ gram) {
  const int idx = blockIdx.x * 256 + threadIdx.x;   // < 9*16384
  const int g = idx >> 14;
  const int cell = idx & (GRAM_N - 1);
  const unsigned short* p = part + (size_t)g * KCHUNKS * GRAM_N + cell;
  float s = 0.f;
#pragma unroll
  for (int c = 0; c < KCHUNKS; c++) s += bf2f(p[(size_t)c * GRAM_N]);
  gram[idx] = s;
}

// ---------------------------------------------------------------------------
// Kernel 3: Sinkhorn, split per (pair, kind). kind0: ft||gt; kind1: faa;
// kind2: gbb. Cost matrix in LDS as bf16 rows padded to 132.
// ---------------------------------------------------------------------------
__global__ __launch_bounds__(256) void sinkhorn_part_kernel(
    const float* __restrict__ gram, float* __restrict__ kdpart) {
  const int pair = blockIdx.x, kind = blockIdx.y;
  const float* Gxy = gram + (size_t)(3 * pair + 0) * GRAM_N;
  const float* Gxx = gram + (size_t)(3 * pair + 1) * GRAM_N;
  const float* Gyy = gram + (size_t)(3 * pair + 2) * GRAM_N;

  __shared__ unsigned short C[NB][132];     // 33792 B
  __shared__ float nx[NB], ny[NB];
  __shared__ float pot0[NB], pot1[NB];
  __shared__ float np0[NB], np1[NB];
  __shared__ float red[256];

  const int tid = threadIdx.x;
  if (tid < NB) {
    nx[tid] = Gxx[tid * (NB + 1)];
    ny[tid] = Gyy[tid * (NB + 1)];
    pot0[tid] = 0.f; pot1[tid] = 0.f;
  }
  __syncthreads();

  const float* G  = (kind == 0) ? Gxy : ((kind == 1) ? Gxx : Gyy);
  const float* rn = (kind == 2) ? ny : nx;
  const float* cn = (kind == 1) ? nx : ny;
  for (int idx = tid; idx < GRAM_N; idx += 256) {
    const int i = idx >> 7, j = idx & 127;
    const float c = 2.0f * fmaxf(rn[i] + cn[j] - 2.0f * G[idx], 0.0f);
    C[i][j] = f2bf_rn(c);
  }
  __syncthreads();

  const float rho = 250000.0f;
  const float AL = -4.852030263919617f;     // -log(128)
  const int grp = tid >> 7;
  const int i = tid & 127;
  const bool active = (kind == 0) ? true : (grp == 0);
  const bool colread = (kind == 0) && (grp == 1);

  float eps = 1.0f;
  for (int it = 0; it < 9; it++) {
    if (it == 8) eps = 2.5e-5f;             // BLUR^P
    const float inv_eps = 1.0f / eps;
    const float damp = 1.0f / (1.0f + eps / rho);
    const float ebl = eps * AL;

    if (active) {
      const float* h = (kind == 0 && grp == 0) ? pot1 : pot0;
      float m0 = -3.0e38f, m1 = -3.0e38f, m2 = -3.0e38f, m3 = -3.0e38f;
      float s0 = 0.f, s1 = 0.f, s2 = 0.f, s3 = 0.f;
      for (int j = 0; j < NB; j += 4) {
        float c0, c1, c2, c3;
        if (colread) {
          c0 = bf2f(C[j + 0][i]); c1 = bf2f(C[j + 1][i]);
          c2 = bf2f(C[j + 2][i]); c3 = bf2f(C[j + 3][i]);
        } else {
          c0 = bf2f(C[i][j + 0]); c1 = bf2f(C[i][j + 1]);
          c2 = bf2f(C[i][j + 2]); c3 = bf2f(C[i][j + 3]);
        }
        const float u0 = ebl + h[j + 0] - c0;
        const float u1 = ebl + h[j + 1] - c1;
        const float u2 = ebl + h[j + 2] - c2;
        const float u3 = ebl + h[j + 3] - c3;
        float nm;
        nm = fmaxf(m0, u0); s0 = s0 * __expf((m0 - nm) * inv_eps) + __expf((u0 - nm) * inv_eps); m0 = nm;
        nm = fmaxf(m1, u1); s1 = s1 * __expf((m1 - nm) * inv_eps) + __expf((u1 - nm) * inv_eps); m1 = nm;
        nm = fmaxf(m2, u2); s2 = s2 * __expf((m2 - nm) * inv_eps) + __expf((u2 - nm) * inv_eps); m2 = nm;
        nm = fmaxf(m3, u3); s3 = s3 * __expf((m3 - nm) * inv_eps) + __expf((u3 - nm) * inv_eps); m3 = nm;
      }
      const float M = fmaxf(fmaxf(m0, m1), fmaxf(m2, m3));
      const float Ssum = s0 * __expf((m0 - M) * inv_eps) + s1 * __expf((m1 - M) * inv_eps)
                       + s2 * __expf((m2 - M) * inv_eps) + s3 * __expf((m3 - M) * inv_eps);
      const float sm = -(M + eps * __logf(Ssum));
      float newp;
      if (kind == 0) newp = damp * sm;
      else           newp = 0.5f * (pot0[i] + damp * sm);
      if (grp == 0) np0[i] = newp; else np1[i] = newp;
    }
    __syncthreads();
    if (tid < NB) {
      pot0[tid] = np0[tid];
      if (kind == 0) pot1[tid] = np1[tid];
    }
    __syncthreads();
    eps *= 0.25f;                           // SCALING^P
  }

  float v = 0.f;
  if (kind == 0) {
    v = (grp == 0) ? -__expf(-pot0[i] / rho)
                   : -__expf(-pot1[i] / rho);
  } else if (grp == 0) {
    v = __expf(-pot0[i] / rho);
  }
  red[tid] = v;
  __syncthreads();
  for (int st = 128; st > 0; st >>= 1) {
    if (tid < st) red[tid] += red[tid + st];
    __syncthreads();
  }
  if (tid == 0) kdpart[pair * 3 + kind] = red[0];
}

// ---------------------------------------------------------------------------
// Kernel 4: one-hot structure of delta -> gathers. block per (b,s).
// ---------------------------------------------------------------------------
__global__ __launch_bounds__(256) void ps_kernel(
    const float* __restrict__ lc, const float* __restrict__ lt, const float* __restrict__ le,
    const float* __restrict__ batch,
    float* __restrict__ pc, float* __restrict__ pt, float* __restrict__ pe,
    float* __restrict__ aarr) {
  const int bs = blockIdx.x;
  const int b = bs / S_DIM, s = bs % S_DIM;
  const float* brow = batch + ((size_t)b * T_DIM + (s + 1)) * (2 * Q_DIM);
  __shared__ int sq;
  __shared__ float sds;
  if (threadIdx.x == 0) sq = 0;
  __syncthreads();
  for (int q = threadIdx.x; q < Q_DIM; q += 256) {
    float d0 = brow[q], d1 = brow[Q_DIM + q];
    if (d0 + d1 > 0.5f) { sq = q; sds = d0 - d1; }   // exactly one thread fires
  }
  __syncthreads();
  if (threadIdx.x == 0) {
    const size_t off = ((size_t)b * T_DIM + s) * Q_DIM + sq;
    pc[bs] = 2.0f * lc[off];   // 1/TEMP
    pt[bs] = 2.0f * lt[off];
    pe[bs] = 2.0f * le[off];
    aarr[bs] = (sds > 0.0f) ? 1.0f : 0.0f;
  }
}

// ---------------------------------------------------------------------------
// Kernel 5: embed loss: sum of squared diffs.
// ---------------------------------------------------------------------------
__global__ __launch_bounds__(256) void embed_kernel(
    const f32x4* __restrict__ hs, const f32x4* __restrict__ ht,
    const f32x4* __restrict__ ds, const f32x4* __restrict__ dt,
    float* __restrict__ acc) {
  const int N4 = NB * T_DIM * H_DIM / 4;   // 409600
  float sum = 0.f;
  for (int idx = blockIdx.x * 256 + threadIdx.x; idx < N4; idx += gridDim.x * 256) {
    f32x4 a = hs[idx] - ht[idx];
    f32x4 b = ds[idx] - dt[idx];
    sum += a[0]*a[0] + a[1]*a[1] + a[2]*a[2] + a[3]*a[3]
         + b[0]*b[0] + b[1]*b[1] + b[2]*b[2] + b[3]*b[3];
  }
  for (int off = 32; off > 0; off >>= 1) sum += __shfl_down(sum, off, 64);
  __shared__ float wsum[4];
  const int lane = threadIdx.x & 63, wv = threadIdx.x >> 6;
  if (lane == 0) wsum[wv] = sum;
  __syncthreads();
  if (threadIdx.x == 0) atomicAdd(acc, wsum[0] + wsum[1] + wsum[2] + wsum[3]);
}

// ---------------------------------------------------------------------------
// Kernel 6: masked CE + final combine. 1 block, 128 threads.
// ---------------------------------------------------------------------------
__device__ inline float ce_row(const float* __restrict__ x, const float* __restrict__ a, int L) {
  float m = -3.0e38f;
  for (int s = 0; s < L; s++) m = fmaxf(m, x[s]);
  float sum = 0.f;
  for (int s = 0; s < L; s++) sum += __expf(x[s] - m);
  const float lse = m + __logf(sum);
  float loss = 0.f;
  for (int s = 0; s < L; s++) loss += a[s] * (x[s] - lse);
  return -loss;
}

__global__ __launch_bounds__(128) void ce_final_kernel(
    const float* __restrict__ pc, const float* __restrict__ pt, const float* __restrict__ pe,
    const float* __restrict__ aarr, const float* __restrict__ kdpart,
    const float* __restrict__ emb, float* __restrict__ out) {
  const int b = threadIdx.x;
  const float* xc = pc + b * S_DIM;
  const float* xt = pt + b * S_DIM;
  const float* xe = pe + b * S_DIM;
  const float* av = aarr + b * S_DIM;
  int last = -1;
  for (int s = 0; s < S_DIM; s++)
    if (xc[s] > 0.0f) last = s;
  const int L = (last >= 0) ? (last + 1) : S_DIM;
  float loss = ce_row(xt, av, L) + ce_row(xc, av, L) + ce_row(xe, av, L);
  __shared__ float red[128];
  red[b] = loss;
  __syncthreads();
  for (int st = 64; st > 0; st >>= 1) {
    if (b < st) red[b] += red[b + st];
    __syncthreads();
  }
  if (b == 0) {
    float kd = 0.f;
    for (int k = 0; k < 9; k++) kd += kdpart[k];
    // w * a_w = (rho + eps_final/2) / 128 ; DIST_W = 0.01
    out[0] = red[0] + 0.01f * (250000.0000125f / 128.0f) * kd + 0.5f * emb[0];
  }
}

// ---------------------------------------------------------------------------
extern "C" void kernel_launch(void* const* d_in, const int* in_sizes, int n_in,
                              void* d_out, int out_size, void* d_ws, size_t ws_size,
                              hipStream_t stream) {
  const float* lc    = (const float*)d_in[0];
  const float* lt    = (const float*)d_in[1];
  const float* le    = (const float*)d_in[2];
  const float* ltc   = (const float*)d_in[3];
  const float* ltt   = (const float*)d_in[4];
  const float* lte   = (const float*)d_in[5];
  const float* ohs   = (const float*)d_in[6];
  const float* oht   = (const float*)d_in[7];
  const float* ods   = (const float*)d_in[8];
  const float* odt   = (const float*)d_in[9];
  const float* batch = (const float*)d_in[10];

  unsigned short* part = (unsigned short*)d_ws;        // 9*80*16384*2B = 23.6 MB
  float* gram = (float*)(part + (size_t)9 * KCHUNKS * GRAM_N);  // 9*16384 f32
  float* pcb  = gram + 9 * GRAM_N;                     // 128*49 each
  float* ptb  = pcb + NB * S_DIM;
  float* peb  = ptb + NB * S_DIM;
  float* ab   = peb + NB * S_DIM;
  float* kdp  = ab + NB * S_DIM;                       // 9
  float* emb  = kdp + 9;                               // 1

  hipMemsetAsync(emb, 0, sizeof(float), stream);

  embed_kernel<<<512, 256, 0, stream>>>(
      (const f32x4*)ohs, (const f32x4*)oht, (const f32x4*)ods, (const f32x4*)odt, emb);

  ps_kernel<<<NB * S_DIM, 256, 0, stream>>>(lc, lt, le, batch, pcb, ptb, peb, ab);

  gram_fused_kernel<<<dim3(KCHUNKS, 3), 1024, 0, stream>>>(lc, lt, le, ltc, ltt, lte, part);

  gram_reduce_kernel<<<(9 * GRAM_N) / 256, 256, 0, stream>>>(part, gram);

  sinkhorn_part_kernel<<<dim3(3, 3), 256, 0, stream>>>(gram, kdp);

  ce_final_kernel<<<1, 128, 0, stream>>>(pcb, ptb, peb, ab, kdp, emb, (float*)d_out);
}

// Round 5
// 362.411 us; speedup vs baseline: 1.2563x; 1.0401x over previous
//
#include <hip/hip_runtime.h>

#define NB 128
#define T_DIM 50
#define Q_DIM 1024
#define H_DIM 256
#define S_DIM 49                 // MAX_STEP - 1
#define K_DIM 51200              // T*Q
#define KCHUNKS 80
#define KC 640                   // K per block
#define BK 64                    // K per LDS stage
#define NSTAGE 10                // KC/BK
#define GRAM_N (NB * NB)         // 16384
#define LROWU 36                 // uints per padded LDS row (64 f16 + 8 pad)
#define CPAD 132                 // padded f32 row for sinkhorn cost matrix

typedef __attribute__((ext_vector_type(4))) float f32x4;
typedef __attribute__((ext_vector_type(8))) _Float16 half8v;
typedef __attribute__((ext_vector_type(4))) unsigned int uint4v;
typedef __attribute__((ext_vector_type(2))) unsigned int uint2v;
using pk2_t = decltype(__builtin_amdgcn_cvt_pkrtz(0.0f, 0.0f));

union PKU { pk2_t p; unsigned int u; };
union U4H8 { uint4v u; half8v h; };

__device__ inline unsigned short f2bf_rn(float x) {   // round-nearest-even bf16
  union { float f; unsigned int u; } v; v.f = x;
  unsigned int r = v.u + 0x7FFFu + ((v.u >> 16) & 1u);
  return (unsigned short)(r >> 16);
}
__device__ inline float bf2f(unsigned short b) {
  union { float f; unsigned int u; } v; v.u = ((unsigned int)b) << 16;
  return v.f;
}

// ---------------------------------------------------------------------------
// Kernel 1: FUSED per-pair grams (XY, XX, YY) via 16x16x32 f16 MFMA.
// grid = (KCHUNKS, 3 pairs), block = 1024 (16 waves). Each input matrix is
// read exactly once (157 MB total = compulsory). Register-prefetch pipeline.
// ---------------------------------------------------------------------------
__global__ __launch_bounds__(1024) void gram_fused_kernel(
    const float* __restrict__ s0, const float* __restrict__ s1, const float* __restrict__ s2,
    const float* __restrict__ t0, const float* __restrict__ t1, const float* __restrict__ t2,
    unsigned short* __restrict__ part) {
  __shared__ unsigned int panA[NB * LROWU];   // s panel, 18432 B
  __shared__ unsigned int panB[NB * LROWU];   // t panel, 18432 B

  const int chunk = blockIdx.x;
  const int pair = blockIdx.y;
  const float* S  = (pair == 0) ? s0 : ((pair == 1) ? s1 : s2);
  const float* Tm = (pair == 0) ? t0 : ((pair == 1) ? t1 : t2);

  const int tid = threadIdx.x;
  const int wave = tid >> 6, lane = tid & 63;
  const int wrow = wave >> 2, wcol = wave & 3;
  const int l15 = lane & 15, quad = lane >> 4;

  f32x4 aXY[2][2], aXX[2][2], aYY[2][2];
#pragma unroll
  for (int i = 0; i < 2; i++)
#pragma unroll
    for (int j = 0; j < 2; j++) {
      aXY[i][j] = (f32x4){0.f, 0.f, 0.f, 0.f};
      aXX[i][j] = (f32x4){0.f, 0.f, 0.f, 0.f};
      aYY[i][j] = (f32x4){0.f, 0.f, 0.f, 0.f};
    }

  const int r0 = tid >> 4;              // 0..63 (i=0); i=1 -> r0+64
  const int kq = tid & 15;
  const size_t ro0 = (size_t)r0 * K_DIM;
  const size_t ro1 = (size_t)(r0 + 64) * K_DIM;

  const int kbase = chunk * KC;
  f32x4 pre0, pre1, pre2, pre3;

#define ISSUE_LOADS(KPOS)                                    \
  {                                                          \
    const float* pS = S + (KPOS) + kq * 4;                   \
    const float* pT = Tm + (KPOS) + kq * 4;                  \
    pre0 = *(const f32x4*)(pS + ro0);                        \
    pre1 = *(const f32x4*)(pS + ro1);                        \
    pre2 = *(const f32x4*)(pT + ro0);                        \
    pre3 = *(const f32x4*)(pT + ro1);                        \
  }

  ISSUE_LOADS(kbase)

  for (int st = 0; st < NSTAGE; st++) {
    if (st) __syncthreads();            // readers of stage st-1 done
    {                                   // cvt + LDS write
      PKU a, b; uint2v w;
      a.p = __builtin_amdgcn_cvt_pkrtz(pre0[0], pre0[1]);
      b.p = __builtin_amdgcn_cvt_pkrtz(pre0[2], pre0[3]);
      w.x = a.u; w.y = b.u;
      *(uint2v*)&panA[r0 * LROWU + kq * 2] = w;
      a.p = __builtin_amdgcn_cvt_pkrtz(pre1[0], pre1[1]);
      b.p = __builtin_amdgcn_cvt_pkrtz(pre1[2], pre1[3]);
      w.x = a.u; w.y = b.u;
      *(uint2v*)&panA[(r0 + 64) * LROWU + kq * 2] = w;
      a.p = __builtin_amdgcn_cvt_pkrtz(pre2[0], pre2[1]);
      b.p = __builtin_amdgcn_cvt_pkrtz(pre2[2], pre2[3]);
      w.x = a.u; w.y = b.u;
      *(uint2v*)&panB[r0 * LROWU + kq * 2] = w;
      a.p = __builtin_amdgcn_cvt_pkrtz(pre3[0], pre3[1]);
      b.p = __builtin_amdgcn_cvt_pkrtz(pre3[2], pre3[3]);
      w.x = a.u; w.y = b.u;
      *(uint2v*)&panB[(r0 + 64) * LROWU + kq * 2] = w;
    }
    __syncthreads();                    // writes visible
    if (st + 1 < NSTAGE) ISSUE_LOADS(kbase + (st + 1) * BK)

#pragma unroll
    for (int ks = 0; ks < 2; ks++) {
      const int kc = ks * 16 + quad * 4;
      half8v as_[2], bs_[2], at_[2], bt_[2];
#pragma unroll
      for (int t = 0; t < 2; t++) {
        U4H8 u;
        u.u = *(const uint4v*)&panA[(wrow * 32 + t * 16 + l15) * LROWU + kc]; as_[t] = u.h;
        u.u = *(const uint4v*)&panA[(wcol * 32 + t * 16 + l15) * LROWU + kc]; bs_[t] = u.h;
        u.u = *(const uint4v*)&panB[(wrow * 32 + t * 16 + l15) * LROWU + kc]; at_[t] = u.h;
        u.u = *(const uint4v*)&panB[(wcol * 32 + t * 16 + l15) * LROWU + kc]; bt_[t] = u.h;
      }
#pragma unroll
      for (int ti = 0; ti < 2; ti++)
#pragma unroll
        for (int tj = 0; tj < 2; tj++) {
          aXY[ti][tj] = __builtin_amdgcn_mfma_f32_16x16x32_f16(as_[ti], bt_[tj], aXY[ti][tj], 0, 0, 0);
          aXX[ti][tj] = __builtin_amdgcn_mfma_f32_16x16x32_f16(as_[ti], bs_[tj], aXX[ti][tj], 0, 0, 0);
          aYY[ti][tj] = __builtin_amdgcn_mfma_f32_16x16x32_f16(at_[ti], bt_[tj], aYY[ti][tj], 0, 0, 0);
        }
    }
  }
#undef ISSUE_LOADS

#pragma unroll
  for (int kind = 0; kind < 3; kind++) {
    unsigned short* out = part + ((size_t)(pair * 3 + kind) * KCHUNKS + chunk) * GRAM_N;
#pragma unroll
    for (int ti = 0; ti < 2; ti++)
#pragma unroll
      for (int tj = 0; tj < 2; tj++) {
        const f32x4 v = (kind == 0) ? aXY[ti][tj] : ((kind == 1) ? aXX[ti][tj] : aYY[ti][tj]);
        const int col = wcol * 32 + tj * 16 + l15;
#pragma unroll
        for (int r = 0; r < 4; r++) {
          const int row = wrow * 32 + ti * 16 + quad * 4 + r;
          out[(size_t)row * NB + col] = f2bf_rn(v[r]);
        }
      }
  }
}

// ---------------------------------------------------------------------------
// Kernel 2: reduce bf16 K-chunk partials -> gram[9][128][128] (f32)
// ---------------------------------------------------------------------------
__global__ __launch_bounds__(256) void gram_reduce_kernel(
    const unsigned short* __restrict__ part, float* __restrict__ gram) {
  const int idx = blockIdx.x * 256 + threadIdx.x;   // < 9*16384
  const int g = idx >> 14;
  const int cell = idx & (GRAM_N - 1);
  const unsigned short* p = part + (size_t)g * KCHUNKS * GRAM_N + cell;
  float s = 0.f;
#pragma unroll
  for (int c = 0; c < KCHUNKS; c++) s += bf2f(p[(size_t)c * GRAM_N]);
  gram[idx] = s;
}

// ---------------------------------------------------------------------------
// Kernel 3: Sinkhorn, per (pair, kind) chain. kind0: ft||gt; kind1: faa;
// kind2: gbb.
//  - C register-cached per thread (32 x f32x4, f32 exact).
//  - Two-pass softmin: pass1 max (fmax chain), pass2 sum of exp2.
//  - SAFETY (round-4 fix): exponent computed as (u - m) * k, subtract FIRST.
//    Float subtraction is monotone so u<=m => (u-m)<=0 => exp2<=1; the fma
//    form u*k - round(m*k) had rounding residual up to ~1e3 POSITIVE at
//    k~5.8e4 -> exp2(+1e3) = inf (round-4 failure).
// ---------------------------------------------------------------------------
__global__ __launch_bounds__(256, 1) void sinkhorn_part_kernel(
    const float* __restrict__ gram, float* __restrict__ kdpart) {
  const int pair = blockIdx.x, kind = blockIdx.y;
  const float* Gxy = gram + (size_t)(3 * pair + 0) * GRAM_N;
  const float* Gxx = gram + (size_t)(3 * pair + 1) * GRAM_N;
  const float* Gyy = gram + (size_t)(3 * pair + 2) * GRAM_N;

  __shared__ float CL[NB * CPAD];     // 67584 B, f32 cost matrix
  __shared__ f32x4 h4a[NB / 4];       // pot0 (f-side)
  __shared__ f32x4 h4b[NB / 4];       // pot1 (g-side, kind0 only)
  __shared__ float nx[NB], ny[NB];
  __shared__ float red[256];

  const int tid = threadIdx.x;
  if (tid < NB) {
    nx[tid] = Gxx[tid * (NB + 1)];
    ny[tid] = Gyy[tid * (NB + 1)];
    ((float*)h4a)[tid] = 0.f;
    ((float*)h4b)[tid] = 0.f;
  }
  __syncthreads();

  const float* G  = (kind == 0) ? Gxy : ((kind == 1) ? Gxx : Gyy);
  const float* rn = (kind == 2) ? ny : nx;
  const float* cn = (kind == 1) ? nx : ny;
  for (int idx = tid; idx < GRAM_N; idx += 256) {
    const int i = idx >> 7, j = idx & 127;
    CL[i * CPAD + j] = 2.0f * fmaxf(rn[i] + cn[j] - 2.0f * G[idx], 0.0f);
  }
  __syncthreads();

  const float rho = 250000.0f;
  const float AL = -4.852030263919617f;     // -log(128)
  const float LOG2E = 1.4426950408889634f;
  const float LN2 = 0.6931471805599453f;
  const int grp = tid >> 7;
  const int i = tid & 127;
  const bool active = (kind == 0) || (grp == 0);
  const bool colread = (kind == 0) && (grp == 1);

  // register-cache this thread's C row (or column for gt)
  f32x4 crow[32];
  if (active) {
    if (colread) {
#pragma unroll
      for (int jj = 0; jj < 32; jj++) {
        f32x4 v;
        v[0] = CL[(4 * jj + 0) * CPAD + i];
        v[1] = CL[(4 * jj + 1) * CPAD + i];
        v[2] = CL[(4 * jj + 2) * CPAD + i];
        v[3] = CL[(4 * jj + 3) * CPAD + i];
        crow[jj] = v;
      }
    } else {
#pragma unroll
      for (int jj = 0; jj < 32; jj++)
        crow[jj] = *(const f32x4*)&CL[i * CPAD + 4 * jj];
    }
  }

  float eps = 1.0f;
  for (int it = 0; it < 9; it++) {
    if (it == 8) eps = 2.5e-5f;             // BLUR^P
    const float inv_eps = 1.0f / eps;
    const float damp = 1.0f / (1.0f + eps / rho);
    const float ebl = eps * AL;

    float newp = 0.f;
    if (active) {
      const f32x4* h = (kind == 0 && grp == 0) ? h4b : h4a;
      // pass 1: m = max_j (h[j] - C[j])
      f32x4 m4 = (f32x4){-3.0e38f, -3.0e38f, -3.0e38f, -3.0e38f};
#pragma unroll
      for (int jj = 0; jj < 32; jj++) {
        const f32x4 u = h[jj] - crow[jj];
        m4[0] = fmaxf(m4[0], u[0]); m4[1] = fmaxf(m4[1], u[1]);
        m4[2] = fmaxf(m4[2], u[2]); m4[3] = fmaxf(m4[3], u[3]);
      }
      const float m = fmaxf(fmaxf(m4[0], m4[1]), fmaxf(m4[2], m4[3]));
      // pass 2: S = sum_j exp2((u - m) * k); subtract-first keeps arg <= 0
      const float k = inv_eps * LOG2E;
      f32x4 s4 = (f32x4){0.f, 0.f, 0.f, 0.f};
#pragma unroll
      for (int jj = 0; jj < 32; jj++) {
        const f32x4 u = h[jj] - crow[jj];
        s4[0] += __builtin_exp2f((u[0] - m) * k);
        s4[1] += __builtin_exp2f((u[1] - m) * k);
        s4[2] += __builtin_exp2f((u[2] - m) * k);
        s4[3] += __builtin_exp2f((u[3] - m) * k);
      }
      const float Ssum = (s4[0] + s4[1]) + (s4[2] + s4[3]);   // >= 1
      // softmin = -(m + ebl + eps*ln(S))
      const float sm = -(m + ebl + eps * (LN2 * __log2f(Ssum)));
      if (kind == 0) newp = damp * sm;
      else           newp = 0.5f * (((const float*)h4a)[i] + damp * sm);
    }
    __syncthreads();                        // all reads of h done
    if (active) {
      if (grp == 0) ((float*)h4a)[i] = newp;
      else          ((float*)h4b)[i] = newp;
    }
    __syncthreads();                        // new pots visible
    eps *= 0.25f;                           // SCALING^P
  }

  float v = 0.f;
  if (kind == 0) {
    v = (grp == 0) ? -__expf(-((const float*)h4a)[i] / rho)
                   : -__expf(-((const float*)h4b)[i] / rho);
  } else if (grp == 0) {
    v = __expf(-((const float*)h4a)[i] / rho);
  }
  red[tid] = v;
  __syncthreads();
  for (int st = 128; st > 0; st >>= 1) {
    if (tid < st) red[tid] += red[tid + st];
    __syncthreads();
  }
  if (tid == 0) kdpart[pair * 3 + kind] = red[0];
}

// ---------------------------------------------------------------------------
// Kernel 4: one-hot structure of delta -> gathers. block per (b,s).
// ---------------------------------------------------------------------------
__global__ __launch_bounds__(256) void ps_kernel(
    const float* __restrict__ lc, const float* __restrict__ lt, const float* __restrict__ le,
    const float* __restrict__ batch,
    float* __restrict__ pc, float* __restrict__ pt, float* __restrict__ pe,
    float* __restrict__ aarr) {
  const int bs = blockIdx.x;
  const int b = bs / S_DIM, s = bs % S_DIM;
  const float* brow = batch + ((size_t)b * T_DIM + (s + 1)) * (2 * Q_DIM);
  __shared__ int sq;
  __shared__ float sds;
  if (threadIdx.x == 0) sq = 0;
  __syncthreads();
  for (int q = threadIdx.x; q < Q_DIM; q += 256) {
    float d0 = brow[q], d1 = brow[Q_DIM + q];
    if (d0 + d1 > 0.5f) { sq = q; sds = d0 - d1; }   // exactly one thread fires
  }
  __syncthreads();
  if (threadIdx.x == 0) {
    const size_t off = ((size_t)b * T_DIM + s) * Q_DIM + sq;
    pc[bs] = 2.0f * lc[off];   // 1/TEMP
    pt[bs] = 2.0f * lt[off];
    pe[bs] = 2.0f * le[off];
    aarr[bs] = (sds > 0.0f) ? 1.0f : 0.0f;
  }
}

// ---------------------------------------------------------------------------
// Kernel 5: embed loss: sum of squared diffs.
// ---------------------------------------------------------------------------
__global__ __launch_bounds__(256) void embed_kernel(
    const f32x4* __restrict__ hs, const f32x4* __restrict__ ht,
    const f32x4* __restrict__ ds, const f32x4* __restrict__ dt,
    float* __restrict__ acc) {
  const int N4 = NB * T_DIM * H_DIM / 4;   // 409600
  float sum = 0.f;
  for (int idx = blockIdx.x * 256 + threadIdx.x; idx < N4; idx += gridDim.x * 256) {
    f32x4 a = hs[idx] - ht[idx];
    f32x4 b = ds[idx] - dt[idx];
    sum += a[0]*a[0] + a[1]*a[1] + a[2]*a[2] + a[3]*a[3]
         + b[0]*b[0] + b[1]*b[1] + b[2]*b[2] + b[3]*b[3];
  }
  for (int off = 32; off > 0; off >>= 1) sum += __shfl_down(sum, off, 64);
  __shared__ float wsum[4];
  const int lane = threadIdx.x & 63, wv = threadIdx.x >> 6;
  if (lane == 0) wsum[wv] = sum;
  __syncthreads();
  if (threadIdx.x == 0) atomicAdd(acc, wsum[0] + wsum[1] + wsum[2] + wsum[3]);
}

// ---------------------------------------------------------------------------
// Kernel 6: masked CE + final combine. 1 block, 128 threads.
// ---------------------------------------------------------------------------
__device__ inline float ce_row(const float* __restrict__ x, const float* __restrict__ a, int L) {
  float m = -3.0e38f;
  for (int s = 0; s < L; s++) m = fmaxf(m, x[s]);
  float sum = 0.f;
  for (int s = 0; s < L; s++) sum += __expf(x[s] - m);
  const float lse = m + __logf(sum);
  float loss = 0.f;
  for (int s = 0; s < L; s++) loss += a[s] * (x[s] - lse);
  return -loss;
}

__global__ __launch_bounds__(128) void ce_final_kernel(
    const float* __restrict__ pc, const float* __restrict__ pt, const float* __restrict__ pe,
    const float* __restrict__ aarr, const float* __restrict__ kdpart,
    const float* __restrict__ emb, float* __restrict__ out) {
  const int b = threadIdx.x;
  const float* xc = pc + b * S_DIM;
  const float* xt = pt + b * S_DIM;
  const float* xe = pe + b * S_DIM;
  const float* av = aarr + b * S_DIM;
  int last = -1;
  for (int s = 0; s < S_DIM; s++)
    if (xc[s] > 0.0f) last = s;
  const int L = (last >= 0) ? (last + 1) : S_DIM;
  float loss = ce_row(xt, av, L) + ce_row(xc, av, L) + ce_row(xe, av, L);
  __shared__ float red[128];
  red[b] = loss;
  __syncthreads();
  for (int st = 64; st > 0; st >>= 1) {
    if (b < st) red[b] += red[b + st];
    __syncthreads();
  }
  if (b == 0) {
    float kd = 0.f;
    for (int k = 0; k < 9; k++) kd += kdpart[k];
    // w * a_w = (rho + eps_final/2) / 128 ; DIST_W = 0.01
    out[0] = red[0] + 0.01f * (250000.0000125f / 128.0f) * kd + 0.5f * emb[0];
  }
}

// ---------------------------------------------------------------------------
extern "C" void kernel_launch(void* const* d_in, const int* in_sizes, int n_in,
                              void* d_out, int out_size, void* d_ws, size_t ws_size,
                              hipStream_t stream) {
  const float* lc    = (const float*)d_in[0];
  const float* lt    = (const float*)d_in[1];
  const float* le    = (const float*)d_in[2];
  const float* ltc   = (const float*)d_in[3];
  const float* ltt   = (const float*)d_in[4];
  const float* lte   = (const float*)d_in[5];
  const float* ohs   = (const float*)d_in[6];
  const float* oht   = (const float*)d_in[7];
  const float* ods   = (const float*)d_in[8];
  const float* odt   = (const float*)d_in[9];
  const float* batch = (const float*)d_in[10];

  unsigned short* part = (unsigned short*)d_ws;        // 9*80*16384*2B = 23.6 MB
  float* gram = (float*)(part + (size_t)9 * KCHUNKS * GRAM_N);  // 9*16384 f32
  float* pcb  = gram + 9 * GRAM_N;                     // 128*49 each
  float* ptb  = pcb + NB * S_DIM;
  float* peb  = ptb + NB * S_DIM;
  float* ab   = peb + NB * S_DIM;
  float* kdp  = ab + NB * S_DIM;                       // 9
  float* emb  = kdp + 9;                               // 1

  hipMemsetAsync(emb, 0, sizeof(float), stream);

  embed_kernel<<<512, 256, 0, stream>>>(
      (const f32x4*)ohs, (const f32x4*)oht, (const f32x4*)ods, (const f32x4*)odt, emb);

  ps_kernel<<<NB * S_DIM, 256, 0, stream>>>(lc, lt, le, batch, pcb, ptb, peb, ab);

  gram_fused_kernel<<<dim3(KCHUNKS, 3), 1024, 0, stream>>>(lc, lt, le, ltc, ltt, lte, part);

  gram_reduce_kernel<<<(9 * GRAM_N) / 256, 256, 0, stream>>>(part, gram);

  sinkhorn_part_kernel<<<dim3(3, 3), 256, 0, stream>>>(gram, kdp);

  ce_final_kernel<<<1, 128, 0, stream>>>(pcb, ptb, peb, ab, kdp, emb, (float*)d_out);
}